// Round 9
// baseline (61.722 us; speedup 1.0000x reference)
//
#include <hip/hip_runtime.h>

// YOLOv1 loss, MI355X. input/target (4096,14,14,30) f32 -> scalar f32 (loss/4096).
// Round 9: pure streaming, zero LDS / zero cross-lane / zero explicit waits.
// Two cells = 240 B = exactly 15 float4. 15-lane groups own a cell-pair; lane's
// float4 slot j = lane%15 is loop-invariant -> its 4 channels' weights (per
// mask-state) and sqrt-flags precomputed in registers. Mask state comes from two
// direct 8 B conf loads at the pair base (L1-hit: the wave streams those lines),
// so the inner loop is load->VALU only and pipelines deep.
// 6272 waves x 16 iters x 4 cell-pairs = 401408 pairs = 802816 cells exactly.

#define COORD 5.0f
#define NOOBJ 0.5f

#define THREADS 256
#define GRID    1568                 // 6272 waves
#define ITERS   16                   // 4 cell-pairs per wave-iter (60 active lanes)

__global__ __launch_bounds__(THREADS) void yolo_loss_kernel(
    const float* __restrict__ inp,
    const float* __restrict__ tgt,
    float* __restrict__ out,
    float inv_n)
{
    __shared__ float wsum[THREADS / 64];

    const int tid  = threadIdx.x;
    const int lane = tid & 63;
    const int wv   = blockIdx.x * (THREADS / 64) + (tid >> 6);   // 0..6271

    const int l4 = (lane < 60) ? lane : 59;    // idle lanes duplicate lane 59
    const int g  = l4 / 15;                    // cell-pair slot within wave-iter (0..3)
    const int j  = l4 % 15;                    // float4 slot within 240B pair (loop-inv)
    const float active = (lane < 60) ? 1.0f : 0.0f;

    // per-f channel constants: glob = 4j+f in [0,60), cell cf = glob/30, ch = glob%30
    float wA[4], wB[4], wN[4];   // weight when state==1 / state==2 / state==0
    float whf[4];                // 1.0 if (w,h) channel -> sqrt-diff form
    int   cf[4];
#pragma unroll
    for (int f = 0; f < 4; ++f) {
        int glob = 4 * j + f;
        int ch = glob % 30;
        cf[f] = glob / 30;
        float a = 0.f, b = 0.f, n = 0.f;
        if (ch == 0)            { a = 1.f;   b = 0.f;   n = NOOBJ; }
        else if (ch == 1)       { a = 0.f;   b = 1.f;   n = NOOBJ; }
        else if (ch <= 5)       { a = COORD; b = 0.f;   n = 0.f;   }  // x0 y0 w0 h0
        else if (ch <= 9)       { a = 0.f;   b = COORD; n = 0.f;   }  // x1 y1 w1 h1
        else                    { a = 1.f;   b = 1.f;   n = 0.f;   }  // classes
        wA[f] = a; wB[f] = b; wN[f] = n;
        whf[f] = (ch == 4 || ch == 5 || ch == 8 || ch == 9) ? 1.0f : 0.0f;
    }

    const float4* ia4 = (const float4*)inp;
    const float4* ta4 = (const float4*)tgt;
    const float2* tc2 = (const float2*)tgt;

    const int p0 = wv * (4 * ITERS) + g;       // this lane's first cell-pair index

    float acc = 0.f;
#pragma unroll 4
    for (int i = 0; i < ITERS; ++i) {
        const int p = p0 + 4 * i;              // cell-pair index
        float4 a = ia4[(size_t)p * 15 + j];
        float4 b = ta4[(size_t)p * 15 + j];
        float2 c0 = tc2[(size_t)p * 30];       // target conf of cell 0 (L1-hit)
        float2 c1 = tc2[(size_t)p * 30 + 15];  // target conf of cell 1 (L1-hit)

        int s0 = (c0.x == 1.0f) ? 1 : ((c0.y == 1.0f) ? 2 : 0);
        int s1 = (c1.x == 1.0f) ? 1 : ((c1.y == 1.0f) ? 2 : 0);

        const float av[4] = {a.x, a.y, a.z, a.w};
        const float bv[4] = {b.x, b.y, b.z, b.w};
#pragma unroll
        for (int f = 0; f < 4; ++f) {
            float x = av[f], y = bv[f];
            float d  = x - y;
            float e_sq = d * d;
            float e_wh = x + y - 2.0f * sqrtf(x * y);   // (sqrt x - sqrt y)^2
            float e = whf[f] * e_wh + (1.0f - whf[f]) * e_sq;
            int s = cf[f] ? s1 : s0;
            float w = (s == 1) ? wA[f] : ((s == 2) ? wB[f] : wN[f]);
            acc = fmaf(w, e, acc);
        }
    }
    acc *= active;

    // ---- wave shfl reduce -> LDS -> one atomic per block ----
#pragma unroll
    for (int off = 32; off > 0; off >>= 1)
        acc += __shfl_down(acc, off, 64);
    if (lane == 0) wsum[tid >> 6] = acc;
    __syncthreads();
    if (tid == 0)
        atomicAdd(out, (wsum[0] + wsum[1] + wsum[2] + wsum[3]) * inv_n);
}

extern "C" void kernel_launch(void* const* d_in, const int* in_sizes, int n_in,
                              void* d_out, int out_size, void* d_ws, size_t ws_size,
                              hipStream_t stream) {
    const float* inp = (const float*)d_in[0];
    const float* tgt = (const float*)d_in[1];
    float* out = (float*)d_out;

    hipMemsetAsync(out, 0, sizeof(float), stream);
    yolo_loss_kernel<<<GRID, THREADS, 0, stream>>>(inp, tgt, out, 1.0f / 4096.0f);
}

// Round 10
// 57.478 us; speedup vs baseline: 1.0738x; 1.0738x over previous
//
#include <hip/hip_runtime.h>

// YOLOv1 loss, MI355X. input/target (4096,14,14,30) f32 -> scalar f32 (loss/4096).
// Round 10: R3's exact pipeline (best measured: 42.4us, 4.55 TB/s effective)
// with its single measured defect removed. Structure: 1-wave blocks (zero
// barriers), GRID=512 -> 2 blocks/CU, 128-cell chunks, 30x width-16
// global_load_lds per chunk, stage-next-then-vmcnt(30) double buffer.
// Compute: R6/R8-validated conflict-free 2-lanes-per-cell stride-15-dword LDS
// mapping (replaces R3's 240B-stride ds_read_b128, which cost 1.84M 8-way
// bank-conflict cycles).

#define COORD 5.0f
#define NOOBJ 0.5f

#define NCELLS   (4096 * 14 * 14)   // 802816
#define CPC      128                // cells per chunk (per wave)
#define CHB      (CPC * 120)        // 15360 B per tensor per chunk
#define NCHUNKS  (NCELLS / CPC)     // 6272
#define GRID     512                // 2 blocks/CU; 12-13 chunks per wave

__device__ __forceinline__ float d2f(float a, float b) { float d = a - b; return d * d; }
__device__ __forceinline__ float sqd(float a, float b) {
    // (sqrt(a)-sqrt(b))^2 = a + b - 2*sqrt(a*b);  a,b >= 0
    return a + b - 2.0f * sqrtf(a * b);
}

__global__ __launch_bounds__(64) void yolo_loss_kernel(
    const float* __restrict__ inp,
    const float* __restrict__ tgt,
    float* __restrict__ out,
    float inv_n)
{
    __shared__ __align__(16) char smem[2][2][CHB];   // [dbuf][tensor][bytes] = 61440 B
    const int lane = threadIdx.x;

    const char* gi0 = (const char*)inp + (size_t)lane * 16;
    const char* gt0 = (const char*)tgt + (size_t)lane * 16;

    // stage chunk c (both tensors, 30 width-16 instructions) into buffer b
    auto stage = [&](int b, int c) {
        const char* gi = gi0 + (size_t)c * CHB;
        const char* gt = gt0 + (size_t)c * CHB;
        char* li = &smem[b][0][0];
        char* lt = &smem[b][1][0];
#pragma unroll
        for (int k = 0; k < 15; ++k) {
            __builtin_amdgcn_global_load_lds(
                (const __attribute__((address_space(1))) void*)(gi + k * 1024),
                (__attribute__((address_space(3))) void*)(li + k * 1024), 16, 0, 0);
            __builtin_amdgcn_global_load_lds(
                (const __attribute__((address_space(1))) void*)(gt + k * 1024),
                (__attribute__((address_space(3))) void*)(lt + k * 1024), 16, 0, 0);
        }
    };

    float acc = 0.0f;
    int c = blockIdx.x;              // GRID <= NCHUNKS, always valid
    stage(0, c);
    int buf = 0;

    const int half = lane & 1;

    for (; c < NCHUNKS; c += GRID) {
        const int cn = c + GRID;
        if (cn < NCHUNKS) {
            stage(buf ^ 1, cn);
            asm volatile("s_waitcnt vmcnt(30)" ::: "memory");   // current chunk landed
        } else {
            asm volatile("s_waitcnt vmcnt(0)" ::: "memory");
        }

        const float* li = (const float*)&smem[buf][0][0];
        const float* lt = (const float*)&smem[buf][1][0];

#pragma unroll
        for (int pass = 0; pass < 4; ++pass) {
            const int p    = (lane >> 1) + 32 * pass;     // cell 0..127
            const int base = 15 * lane + 960 * pass;      // = 30p + 15*half
            const float* ip = li + base;
            const float* tp = lt + base;

            // masks from target conf (pair-broadcast reads, conflict-free)
            float t0 = lt[p * 30];
            float t1 = lt[p * 30 + 1];
            bool o0 = (t0 == 1.0f), o1 = (t1 == 1.0f);
            float f0 = o0 ? 1.0f : 0.0f;
            float f1 = (o1 && !o0) ? 1.0f : 0.0f;
            float h  = (o0 || o1) ? 1.0f : 0.0f;
            float nf = 1.0f - h;

            if (half == 0) {
                // channels 0..14: conf0 conf1 | x0 y0 w0 h0 | x1 y1 w1 h1 | cls0..4
                float s0  = d2f(ip[0], tp[0]);
                float s1  = d2f(ip[1], tp[1]);
                float xy0 = d2f(ip[2], tp[2]) + d2f(ip[3], tp[3]);
                float wh0 = sqd(ip[4], tp[4]) + sqd(ip[5], tp[5]);
                float xy1 = d2f(ip[6], tp[6]) + d2f(ip[7], tp[7]);
                float wh1 = sqd(ip[8], tp[8]) + sqd(ip[9], tp[9]);
                float cls = d2f(ip[10], tp[10]) + d2f(ip[11], tp[11]) + d2f(ip[12], tp[12])
                          + d2f(ip[13], tp[13]) + d2f(ip[14], tp[14]);
                acc += COORD * (f0 * (xy0 + wh0) + f1 * (xy1 + wh1))
                     + f0 * s0 + f1 * s1
                     + NOOBJ * nf * (s0 + s1)
                     + h * cls;
            } else {
                // channels 15..29: cls5..cls19
                float cls = 0.0f;
#pragma unroll
                for (int j = 0; j < 15; ++j)
                    cls += d2f(ip[j], tp[j]);
                acc += h * cls;
            }
        }

        buf ^= 1;
    }

    // ---- wave reduce (block == 1 wave) ----
#pragma unroll
    for (int off = 32; off > 0; off >>= 1)
        acc += __shfl_down(acc, off, 64);
    if (lane == 0) atomicAdd(out, acc * inv_n);
}

extern "C" void kernel_launch(void* const* d_in, const int* in_sizes, int n_in,
                              void* d_out, int out_size, void* d_ws, size_t ws_size,
                              hipStream_t stream) {
    const float* inp = (const float*)d_in[0];
    const float* tgt = (const float*)d_in[1];
    float* out = (float*)d_out;

    hipMemsetAsync(out, 0, sizeof(float), stream);
    yolo_loss_kernel<<<GRID, 64, 0, stream>>>(inp, tgt, out, 1.0f / 4096.0f);
}

// Round 11
// 39.783 us; speedup vs baseline: 1.5515x; 1.4448x over previous
//
#include <hip/hip_runtime.h>

// YOLOv1 loss, MI355X. input/target (4096,14,14,30) f32 -> scalar f32 (loss/4096).
// Round 11: producer/consumer split on R3's champion pipeline (42.4us, 7.2 B/cyc/CU).
// Measured residual in R3: both resident waves compute in lockstep -> memory pipe
// idles ~2300cyc/iter. Fix: wave0 = pure stager (30x width-16 global_load_lds per
// chunk, double-buffered, counted vmcnt(30), re-issues immediately after hand-off),
// wave1 = pure computer (R3's verbatim 2-cells-per-thread b128 compute; its bank
// conflicts are now off the critical path). Two raw s_barriers per chunk.

#define COORD 5.0f
#define NOOBJ 0.5f

#define NCELLS   (4096 * 14 * 14)   // 802816
#define CPC      128                // cells per chunk
#define CHB      (CPC * 120)        // 15360 B per tensor per chunk
#define NCHUNKS  (NCELLS / CPC)     // 6272
#define GRID     512                // 2 blocks/CU; 12-13 chunks per block

__device__ __forceinline__ float d2f(float a, float b) { float d = a - b; return d * d; }
__device__ __forceinline__ float sqd(float a, float b) {
    // (sqrt(a)-sqrt(b))^2 = a + b - 2*sqrt(a*b);  a,b >= 0
    return a + b - 2.0f * sqrtf(a * b);
}

__global__ __launch_bounds__(128) void yolo_loss_kernel(
    const float* __restrict__ inp,
    const float* __restrict__ tgt,
    float* __restrict__ out,
    float inv_n)
{
    __shared__ __align__(16) char smem[2][2][CHB];   // [dbuf][tensor][bytes] = 61440 B
    const int tid  = threadIdx.x;
    const int lane = tid & 63;
    const int wid  = tid >> 6;       // 0 = stager, 1 = computer

    const char* gi0 = (const char*)inp + (size_t)lane * 16;
    const char* gt0 = (const char*)tgt + (size_t)lane * 16;

    auto stage = [&](int b, int c) {
        const char* gi = gi0 + (size_t)c * CHB;
        const char* gt = gt0 + (size_t)c * CHB;
        char* li = &smem[b][0][0];
        char* lt = &smem[b][1][0];
#pragma unroll
        for (int k = 0; k < 15; ++k) {
            __builtin_amdgcn_global_load_lds(
                (const __attribute__((address_space(1))) void*)(gi + k * 1024),
                (__attribute__((address_space(3))) void*)(li + k * 1024), 16, 0, 0);
            __builtin_amdgcn_global_load_lds(
                (const __attribute__((address_space(1))) void*)(gt + k * 1024),
                (__attribute__((address_space(3))) void*)(lt + k * 1024), 16, 0, 0);
        }
    };

    float acc = 0.0f;
    int c = blockIdx.x;
    if (wid == 0) stage(0, c);       // prologue: chunk c in flight (30 outstanding)
    int buf = 0;

    for (; c < NCHUNKS; c += GRID) {
        if (wid == 0) {
            const int cn = c + GRID;
            if (cn < NCHUNKS) {
                stage(buf ^ 1, cn);                                 // 60 outstanding
                asm volatile("s_waitcnt vmcnt(30)" ::: "memory");   // chunk c landed
            } else {
                asm volatile("s_waitcnt vmcnt(0)" ::: "memory");
            }
        }
        asm volatile("s_barrier" ::: "memory");      // hand chunk c to computer

        if (wid == 1) {
            const float4* ia = (const float4*)(&smem[buf][0][0] + lane * 240);
            const float4* ta = (const float4*)(&smem[buf][1][0] + lane * 240);

            float4 I0 = ia[0],  T0 = ta[0];    // A: conf0 conf1 x0 y0
            float4 I1 = ia[1],  T1 = ta[1];    // A: w0 h0 x1 y1
            float4 I2 = ia[2],  T2 = ta[2];    // A: w1 h1 cls0 cls1
            float4 I3 = ia[3],  T3 = ta[3];
            float4 I4 = ia[4],  T4 = ta[4];
            float4 I5 = ia[5],  T5 = ta[5];
            float4 I6 = ia[6],  T6 = ta[6];
            float4 I7 = ia[7],  T7 = ta[7];    // A cls18 cls19 | B conf0 conf1
            float4 I8 = ia[8],  T8 = ta[8];    // B: x0 y0 w0 h0
            float4 I9 = ia[9],  T9 = ta[9];    // B: x1 y1 w1 h1
            float4 I10 = ia[10], T10 = ta[10];
            float4 I11 = ia[11], T11 = ta[11];
            float4 I12 = ia[12], T12 = ta[12];
            float4 I13 = ia[13], T13 = ta[13];
            float4 I14 = ia[14], T14 = ta[14];

            // ---- cell A ----
            {
                bool o0 = (T0.x == 1.0f), o1 = (T0.y == 1.0f);
                float f0 = o0 ? 1.0f : 0.0f;
                float f1 = (o1 && !o0) ? 1.0f : 0.0f;
                float nf = (o0 || o1) ? 0.0f : 1.0f;
                float h  = 1.0f - nf;
                float s0 = d2f(I0.x, T0.x), s1 = d2f(I0.y, T0.y);
                float xy0 = d2f(I0.z, T0.z) + d2f(I0.w, T0.w);
                float wh0 = sqd(I1.x, T1.x) + sqd(I1.y, T1.y);
                float xy1 = d2f(I1.z, T1.z) + d2f(I1.w, T1.w);
                float wh1 = sqd(I2.x, T2.x) + sqd(I2.y, T2.y);
                float cls = d2f(I2.z, T2.z) + d2f(I2.w, T2.w)
                          + d2f(I3.x, T3.x) + d2f(I3.y, T3.y) + d2f(I3.z, T3.z) + d2f(I3.w, T3.w)
                          + d2f(I4.x, T4.x) + d2f(I4.y, T4.y) + d2f(I4.z, T4.z) + d2f(I4.w, T4.w)
                          + d2f(I5.x, T5.x) + d2f(I5.y, T5.y) + d2f(I5.z, T5.z) + d2f(I5.w, T5.w)
                          + d2f(I6.x, T6.x) + d2f(I6.y, T6.y) + d2f(I6.z, T6.z) + d2f(I6.w, T6.w)
                          + d2f(I7.x, T7.x) + d2f(I7.y, T7.y);
                acc += COORD * (f0 * (xy0 + wh0) + f1 * (xy1 + wh1))
                     + f0 * s0 + f1 * s1
                     + NOOBJ * nf * (s0 + s1)
                     + h * cls;
            }
            // ---- cell B ----
            {
                bool o0 = (T7.z == 1.0f), o1 = (T7.w == 1.0f);
                float f0 = o0 ? 1.0f : 0.0f;
                float f1 = (o1 && !o0) ? 1.0f : 0.0f;
                float nf = (o0 || o1) ? 0.0f : 1.0f;
                float h  = 1.0f - nf;
                float s0 = d2f(I7.z, T7.z), s1 = d2f(I7.w, T7.w);
                float xy0 = d2f(I8.x, T8.x) + d2f(I8.y, T8.y);
                float wh0 = sqd(I8.z, T8.z) + sqd(I8.w, T8.w);
                float xy1 = d2f(I9.x, T9.x) + d2f(I9.y, T9.y);
                float wh1 = sqd(I9.z, T9.z) + sqd(I9.w, T9.w);
                float cls = d2f(I10.x, T10.x) + d2f(I10.y, T10.y) + d2f(I10.z, T10.z) + d2f(I10.w, T10.w)
                          + d2f(I11.x, T11.x) + d2f(I11.y, T11.y) + d2f(I11.z, T11.z) + d2f(I11.w, T11.w)
                          + d2f(I12.x, T12.x) + d2f(I12.y, T12.y) + d2f(I12.z, T12.z) + d2f(I12.w, T12.w)
                          + d2f(I13.x, T13.x) + d2f(I13.y, T13.y) + d2f(I13.z, T13.z) + d2f(I13.w, T13.w)
                          + d2f(I14.x, T14.x) + d2f(I14.y, T14.y) + d2f(I14.z, T14.z) + d2f(I14.w, T14.w);
                acc += COORD * (f0 * (xy0 + wh0) + f1 * (xy1 + wh1))
                     + f0 * s0 + f1 * s1
                     + NOOBJ * nf * (s0 + s1)
                     + h * cls;
            }
        }

        asm volatile("s_barrier" ::: "memory");      // computer done with buf
        buf ^= 1;
    }

    // ---- reduction: computer wave only ----
    if (wid == 1) {
#pragma unroll
        for (int off = 32; off > 0; off >>= 1)
            acc += __shfl_down(acc, off, 64);
        if (lane == 0) atomicAdd(out, acc * inv_n);
    }
}

extern "C" void kernel_launch(void* const* d_in, const int* in_sizes, int n_in,
                              void* d_out, int out_size, void* d_ws, size_t ws_size,
                              hipStream_t stream) {
    const float* inp = (const float*)d_in[0];
    const float* tgt = (const float*)d_in[1];
    float* out = (float*)d_out;

    hipMemsetAsync(out, 0, sizeof(float), stream);
    yolo_loss_kernel<<<GRID, 128, 0, stream>>>(inp, tgt, out, 1.0f / 4096.0f);
}